// Round 14
// baseline (1263.982 us; speedup 1.0000x reference)
//
#include <hip/hip_runtime.h>
#include <hip/hip_bf16.h>
#include <math.h>

#define EPS_BN 1e-5f

typedef __bf16 bf16x8 __attribute__((ext_vector_type(8)));
typedef float f32x4 __attribute__((ext_vector_type(4)));
typedef float f32x2 __attribute__((ext_vector_type(2)));

// async global->LDS, 16B per lane. LDS dest must be wave-uniform base + lane*16
__device__ __forceinline__ void gl2lds16(const void* g, void* l) {
  __builtin_amdgcn_global_load_lds(
      (const __attribute__((address_space(1))) unsigned int*)g,
      (__attribute__((address_space(3))) unsigned int*)l, 16, 0, 0);
}

// ============================================================================
// Fused weight prep (launch 1):
//   blocks [0,1152):    conv2 w -> bf16 [9][32][128][8]  (R12 layout)
//   blocks [1152,1440): conv3 w -> bf16 [9][16][64][8]
//   blocks [1440,1568): W32 = att_w[64,256] @ fc2_w[256,512]
//   block  1568:        b_eff = att_w@(fc2_w@fc1_b + fc2_b) + att_b
// ============================================================================
__global__ void k_prep(const float* __restrict__ c2w,
                       __hip_bfloat16* __restrict__ wt2,
                       const float* __restrict__ c3w,
                       __hip_bfloat16* __restrict__ wt3,
                       const float* __restrict__ attw,
                       const float* __restrict__ fc2w, float* __restrict__ W32,
                       const float* __restrict__ fc1b,
                       const float* __restrict__ fc2b,
                       const float* __restrict__ attb, float* __restrict__ be) {
  const int blk = blockIdx.x, tid = threadIdx.x;
  if (blk < 1152) {  // conv2 wt: [9][32][128][8]
    int idx = blk * 256 + tid;
    int icr = idx & 7;
    int oc = (idx >> 3) & 127;
    int rest = idx >> 10;
    int icg = rest & 31;
    int p = rest >> 5;
    wt2[idx] = __float2bfloat16(c2w[(oc * 256 + icg * 8 + icr) * 9 + p]);
  } else if (blk < 1440) {  // conv3 wt: [9][16][64][8]
    int idx = (blk - 1152) * 256 + tid;
    int icr = idx & 7;
    int oc = (idx >> 3) & 63;
    int rest = idx >> 9;
    int icg = rest & 15;
    int p = rest >> 4;
    wt3[idx] = __float2bfloat16(c3w[(oc * 128 + icg * 8 + icr) * 9 + p]);
  } else if (blk < 1568) {
    int idx = (blk - 1440) * 256 + tid;
    int r = idx >> 9, c = idx & 511;
    float s = 0.f;
    for (int k = 0; k < 256; k++)
      s = fmaf(attw[r * 256 + k], fc2w[k * 512 + c], s);
    W32[idx] = s;
  } else {
    __shared__ float t1[256];
    float s = fc2b[tid];
    for (int k = 0; k < 512; k++) s = fmaf(fc2w[tid * 512 + k], fc1b[k], s);
    t1[tid] = s;
    __syncthreads();
    if (tid < 64) {
      float r = attb[tid];
      for (int k = 0; k < 256; k++) r = fmaf(attw[tid * 256 + k], t1[k], r);
      be[tid] = r;
    }
  }
}

// ============================================================================
// W_eff = W32 @ fc1_w, stored TRANSPOSED [2304][64] (launch 2; needs W32).
// ============================================================================
__global__ void k_weff(const float* __restrict__ W32,
                       const float* __restrict__ A1, float* __restrict__ Wet) {
  int idx = blockIdx.x * 256 + threadIdx.x;  // 64*2304
  int r = idx / 2304, c = idx - r * 2304;
  float s = 0.f;
  for (int k = 0; k < 512; k++) s = fmaf(W32[r * 512 + k], A1[k * 2304 + c], s);
  Wet[c * 64 + r] = s;
}

// ============================================================================
// k_pipe (launch 3): ONE BLOCK PER IMAGE runs the whole pipeline block-locally:
//   conv1 (4 bands) -> conv2 (6 tiles, R12-exact body) -> conv3+attention.
// All intermediates (out1p/out2p) are written and read by the SAME block
// (write-through L1 -> same-XCD L2; __syncthreads drains vmcnt) — no
// cross-block dependency, no barriers, no co-residency requirement.
// Removes 2 launches/chunk of tail-drain serialization; phase skew across
// blocks lets conv1/conv2/attn naturally overlap on a CU.
// LDS union 44032B: conv1 xp | conv2 dbuf 2x20480 | c3attn 2x16384 + act/q.
// c3attn staged in 4 stages of 32 ic (window 784 slots) to fit the union.
// ============================================================================
__global__ __launch_bounds__(256, 2) void k_pipe(
    const float* __restrict__ x, const float* __restrict__ c1w,
    const float* __restrict__ c1b, const float* __restrict__ g1,
    const float* __restrict__ bb1, const float* __restrict__ m1,
    const float* __restrict__ v1, __hip_bfloat16* __restrict__ out1p,
    __hip_bfloat16* __restrict__ out2p, const __hip_bfloat16* __restrict__ wt2,
    const float* __restrict__ c2b, const float* __restrict__ g2,
    const float* __restrict__ bb2, const float* __restrict__ m2,
    const float* __restrict__ v2, const __hip_bfloat16* __restrict__ wt3,
    const float* __restrict__ c3b, const float* __restrict__ g3,
    const float* __restrict__ bb3, const float* __restrict__ m3,
    const float* __restrict__ v3, const float* __restrict__ Wet,
    const float* __restrict__ be, const float* __restrict__ fc3w,
    const float* __restrict__ fc3b, float* __restrict__ out, int b0) {
  __shared__ __align__(16) char smem[44032];
  const int blk = blockIdx.x;
  const int tid = threadIdx.x;
  const int wv = tid >> 6, ln = tid & 63;
  const int lhi = ln >> 4, llo = ln & 15;

  // ========================= phase 1: conv1 (4 bands) =======================
  {
    float* xp = (float*)smem;  // [14][50]
    __hip_bfloat16* ob = out1p + (size_t)blk * (26 * 26 * 256);
    __hip_bfloat16* o2 = out2p + (size_t)blk * (14 * 14 * 128);
    const __hip_bfloat16 z = __float2bfloat16(0.f);
    const float* xb = x + (size_t)blk * 2304;
    float wr[9];
#pragma unroll
    for (int i = 0; i < 9; i++) wr[i] = c1w[tid * 9 + i];
    const float scale = g1[tid] * rsqrtf(v1[tid] + EPS_BN);
    const float bias = (c1b[tid] - m1[tid]) * scale + bb1[tid];
    for (int q = 0; q < 4; q++) {
      __syncthreads();  // xp reuse vs previous band's reads
      // out1p halo zeroing split across bands
      if (q == 0)
        for (int i = tid; i < 26 * 256; i += 256) ob[i] = z;
      if (q == 3)
        for (int i = tid; i < 26 * 256; i += 256) ob[25 * 26 * 256 + i] = z;
      for (int i = tid; i < 6 * 2 * 256; i += 256) {
        int r = 1 + 6 * q + (i >> 9), side = (i >> 8) & 1, c = i & 255;
        ob[(r * 26 + side * 25) * 256 + c] = z;
      }
      // out2p halo zeroing (quartered)
      if (q == 0)
        for (int i = tid; i < 14 * 128; i += 256) o2[i] = z;
      if (q == 1)
        for (int i = tid; i < 14 * 128; i += 256) o2[13 * 14 * 128 + i] = z;
      if (q == 2)
        for (int i = tid; i < 6 * 2 * 128; i += 256) {
          int r = 1 + (i >> 8), side = (i >> 7) & 1, c = i & 127;
          o2[(r * 14 + side * 13) * 128 + c] = z;
        }
      if (q == 3)
        for (int i = tid; i < 6 * 2 * 128; i += 256) {
          int r = 7 + (i >> 8), side = (i >> 7) & 1, c = i & 127;
          o2[(r * 14 + side * 13) * 128 + c] = z;
        }
      for (int i = tid; i < 14 * 50; i += 256) xp[i] = 0.f;
      __syncthreads();
      for (int i = tid; i < 14 * 48; i += 256) {
        int rr = i / 48, c = i - rr * 48;
        int gr = 12 * q - 1 + rr;
        if (gr >= 0 && gr < 48) xp[rr * 50 + c + 1] = xb[gr * 48 + c];
      }
      __syncthreads();
#pragma unroll
      for (int ohl = 0; ohl < 6; ohl++) {
        const int r0 = 2 * ohl;
        f32x2 c01[4];
#pragma unroll
        for (int r = 0; r < 4; r++) c01[r] = *(const f32x2*)&xp[(r0 + r) * 50];
#pragma unroll 4
        for (int ow = 0; ow < 24; ow++) {
          f32x2 c23[4];
#pragma unroll
          for (int r = 0; r < 4; r++)
            c23[r] = *(const f32x2*)&xp[(r0 + r) * 50 + 2 * ow + 2];
          f32x2 s2a = 0.f, s2b = 0.f;  // dh = 0, 1 (packed over dw)
#pragma unroll
          for (int r = 0; r < 4; r++) {
            f32x2 p0 = c01[r], p2 = c23[r];
            f32x2 p1 = {p0.y, p2.x};
            if (r <= 2) {
              s2a += p0 * wr[r * 3 + 0];
              s2a += p1 * wr[r * 3 + 1];
              s2a += p2 * wr[r * 3 + 2];
            }
            if (r >= 1) {
              s2b += p0 * wr[(r - 1) * 3 + 0];
              s2b += p1 * wr[(r - 1) * 3 + 1];
              s2b += p2 * wr[(r - 1) * 3 + 2];
            }
          }
          f32x2 e0 = s2a * scale + bias;  // BN before pool
          f32x2 e1 = s2b * scale + bias;
          float mx = fmaxf(fmaxf(e0.x, e0.y), fmaxf(e1.x, e1.y));
          ob[((6 * q + ohl + 1) * 26 + (ow + 1)) * 256 + tid] =
              __float2bfloat16(fmaxf(mx, 0.f));
#pragma unroll
          for (int r = 0; r < 4; r++) c01[r] = c23[r];
        }
      }
    }
  }

  // ========================= phase 2: conv2 (6 tiles, R12 body) =============
  {
    constexpr int HW = 24, IC = 256, OC = 128, HP = 26, CP = 26;
    constexpr int NCH = 6 * CP * 8;           // 1248
    constexpr int NCHP = (NCH + 255) & ~255;  // 1280
    constexpr int NLD = NCHP / 256;           // 5
    constexpr int NSTG = 4;
    constexpr int ABUF = NCHP * 16;  // 20480
    constexpr int ICG = 32;
    constexpr int EPITCH = OC + 1;
    const int wm = wv >> 1, wn = wv & 1;  // 2x2 wave split
    float* se = (float*)smem;

    const __hip_bfloat16* inb = out1p + (size_t)blk * HP * HP * IC;
    int srcoff[NLD];
#pragma unroll
    for (int i = 0; i < NLD; i++) {
      int ci = tid + i * 256;
      if (ci >= NCH) ci = NCH - 1;
      int kgslot = ci & 7;
      int rest = ci >> 3;
      int c = rest % CP;
      int r = rest / CP;
      int kg = kgslot ^ (c & 7);
      srcoff[i] = (r * HP + c) * IC + kg * 8;  // h0 added per tile
    }
    int spb[3][3], msk[3][3];
#pragma unroll
    for (int mt = 0; mt < 3; mt++) {
      int m = wm * 48 + mt * 16 + llo;
      int hl = m / HW, wl = m % HW;
#pragma unroll
      for (int pw = 0; pw < 3; pw++) {
        spb[mt][pw] = (hl * CP + wl + pw) * 8;
        msk[mt][pw] = (wl + pw) & 7;
      }
    }
    const __hip_bfloat16* wtb = wt2 + (size_t)(lhi * OC + wn * 64 + llo) * 8;

    for (int T = 0; T < 6; T++) {
      const int h0 = T * 4;
      const int toff = h0 * HP * IC;
      __syncthreads();  // smem reuse vs previous tile epilogue / conv1
      f32x4 acc[3][4];
      const f32x4 fz = {0.f, 0.f, 0.f, 0.f};
#pragma unroll
      for (int i = 0; i < 3; i++)
#pragma unroll
        for (int j = 0; j < 4; j++) acc[i][j] = fz;
#pragma unroll
      for (int i = 0; i < NLD; i++)
        gl2lds16(inb + toff + srcoff[i], smem + (tid + i * 256) * 16);
      __syncthreads();
#pragma unroll
      for (int s = 0; s < NSTG; s++) {
        if (s + 1 < NSTG) {
          char* nb = smem + ((s + 1) & 1) * ABUF;
#pragma unroll
          for (int i = 0; i < NLD; i++)
            gl2lds16(inb + toff + srcoff[i] + (s + 1) * 64,
                     nb + (tid + i * 256) * 16);
        }
        const char* cw = smem + (s & 1) * ABUF;
#pragma unroll
        for (int p = 0; p < 9; p++) {
          const int ph = p / 3, pw = p % 3;
#pragma unroll
          for (int ks = 0; ks < 2; ks++) {
            const int kg = ks * 4 + lhi;
            bf16x8 bf[4];
#pragma unroll
            for (int j = 0; j < 4; j++)
              bf[j] =
                  *(const bf16x8*)(wtb +
                                   ((size_t)(p * ICG + s * 8 + ks * 4) * OC) *
                                       8 +
                                   j * 128);
            bf16x8 af[3];
#pragma unroll
            for (int mt = 0; mt < 3; mt++) {
              int slot = spb[mt][pw] + ph * CP * 8 + (kg ^ msk[mt][pw]);
              af[mt] = *(const bf16x8*)(cw + slot * 16);
            }
#pragma unroll
            for (int mt = 0; mt < 3; mt++)
#pragma unroll
              for (int j = 0; j < 4; j++)
                acc[mt][j] = __builtin_amdgcn_mfma_f32_16x16x32_bf16(
                    af[mt], bf[j], acc[mt][j], 0, 0, 0);
          }
        }
        __syncthreads();
      }
      // epilogue: per wm-pass BN+ReLU -> se [48][129], pool, store
      constexpr int OHW = 12;
      constexpr int NP = 1 * OHW * OC;
#pragma unroll
      for (int a = 0; a < 2; a++) {
        if (a) __syncthreads();
        if (wm == a) {
#pragma unroll
          for (int j = 0; j < 4; j++) {
            int n = wn * 64 + j * 16 + llo;
            float scale = g2[n] * rsqrtf(v2[n] + EPS_BN);
            float bias = (c2b[n] - m2[n]) * scale + bb2[n];
#pragma unroll
            for (int mt = 0; mt < 3; mt++)
#pragma unroll
              for (int r = 0; r < 4; r++) {
                int mrow = mt * 16 + lhi * 4 + r;
                se[mrow * EPITCH + n] =
                    fmaxf(acc[mt][j][r] * scale + bias, 0.f);
              }
          }
        }
        __syncthreads();
        for (int sI = tid; sI < NP; sI += 256) {
          int n = sI % OC;
          int ow = (sI / OC) % OHW;
          int mloc = 2 * ow;
          float x0 = se[mloc * EPITCH + n];
          float x1 = se[(mloc + 1) * EPITCH + n];
          float x2 = se[(mloc + HW) * EPITCH + n];
          float x3 = se[(mloc + HW + 1) * EPITCH + n];
          float mx = fmaxf(fmaxf(x0, x1), fmaxf(x2, x3));
          int oh = (h0 >> 1) + a;
          out2p[(((size_t)blk * 14 + oh + 1) * 14 + ow + 1) * OC + n] =
              __float2bfloat16(mx);
        }
      }
    }
  }
  __syncthreads();

  // ========= phase 3: conv3 + BN + ReLU + pool + attention + fc3 ============
  {
    constexpr int HW = 12, IC = 128, OC = 64, HP = 14, CP = 14;
    constexpr int NCH = HP * CP * 4;  // 784 slots (32 ic per stage)
    constexpr int NLD = 4;            // ceil(1024/256); pad slots clamped
    constexpr int NSTG = 4;
    constexpr int ABUF = 16384;  // 1024 slots * 16B
    constexpr int EPITCH = OC + 1;
    float* act = (float*)(smem + 32768);  // [64][37]
    float* qp = (float*)(smem + 42240);   // [4][64]
    float* ql = (float*)(smem + 43264);   // [64]
    float* gm = (float*)(smem + 43520);   // [64]
    float* sc = (float*)(smem + 43776);   // [36]
    float* se = (float*)smem;             // epilogue [48][65] (windows dead)

    const __hip_bfloat16* inb = out2p + (size_t)blk * HP * HP * IC;
    int srcoff[NLD];
#pragma unroll
    for (int i = 0; i < NLD; i++) {
      int ci = tid + i * 256;
      if (ci >= NCH) ci = NCH - 1;
      int kgslot = ci & 3;
      int rest = ci >> 2;
      int c = rest % CP;
      int r = rest / CP;
      int kg = kgslot ^ (c & 3);
      srcoff[i] = (r * HP + c) * IC + kg * 8;  // + s*32 per stage
    }
    int spb[9], wlv[9];
#pragma unroll
    for (int mt = 0; mt < 9; mt++) {
      int m = mt * 16 + llo;
      int hl = m / HW, wl = m % HW;
      spb[mt] = (hl * CP + wl) * 4;
      wlv[mt] = wl;
    }
    const __hip_bfloat16* wtb = wt3 + (size_t)(lhi * OC + wv * 16 + llo) * 8;

    f32x4 acc[9];
    const f32x4 fz = {0.f, 0.f, 0.f, 0.f};
#pragma unroll
    for (int i = 0; i < 9; i++) acc[i] = fz;

#pragma unroll
    for (int i = 0; i < NLD; i++)
      gl2lds16(inb + srcoff[i], smem + (tid + i * 256) * 16);
    __syncthreads();
#pragma unroll
    for (int s = 0; s < NSTG; s++) {
      if (s + 1 < NSTG) {
        char* nb = smem + ((s + 1) & 1) * ABUF;
#pragma unroll
        for (int i = 0; i < NLD; i++)
          gl2lds16(inb + srcoff[i] + (s + 1) * 32, nb + (tid + i * 256) * 16);
      }
      const char* cw = smem + (s & 1) * ABUF;
#pragma unroll
      for (int p = 0; p < 9; p++) {
        const int ph = p / 3, pw = p % 3;
        bf16x8 bf = *(const bf16x8*)(wtb +
                                     ((size_t)(p * 16 + s * 4) * OC) * 8);
#pragma unroll
        for (int mt = 0; mt < 9; mt++) {
          int slot =
              spb[mt] + (ph * CP + pw) * 4 + (lhi ^ ((wlv[mt] + pw) & 3));
          bf16x8 af = *(const bf16x8*)(cw + slot * 16);
          acc[mt] =
              __builtin_amdgcn_mfma_f32_16x16x32_bf16(af, bf, acc[mt], 0, 0, 0);
        }
      }
      __syncthreads();
    }
    // epilogue: 3 passes of 48 rows -> se; pool -> act LDS
    {
      const int n = wv * 16 + llo;
      const float scale = g3[n] * rsqrtf(v3[n] + EPS_BN);
      const float bias = (c3b[n] - m3[n]) * scale + bb3[n];
#pragma unroll
      for (int pz = 0; pz < 3; pz++) {
        if (pz) __syncthreads();
#pragma unroll
        for (int mtl = 0; mtl < 3; mtl++)
#pragma unroll
          for (int r = 0; r < 4; r++) {
            int mrow = mtl * 16 + lhi * 4 + r;
            se[mrow * EPITCH + n] =
                fmaxf(acc[pz * 3 + mtl][r] * scale + bias, 0.f);
          }
        __syncthreads();
        for (int sI = tid; sI < 2 * 6 * 64; sI += 256) {
          int nn = sI % 64;
          int ow = (sI / 64) % 6;
          int ohl = sI / (64 * 6);
          int mloc = (2 * ohl) * HW + 2 * ow;
          float x0 = se[mloc * EPITCH + nn];
          float x1 = se[(mloc + 1) * EPITCH + nn];
          float x2 = se[(mloc + HW) * EPITCH + nn];
          float x3 = se[(mloc + HW + 1) * EPITCH + nn];
          float mx = fmaxf(fmaxf(x0, x1), fmaxf(x2, x3));
          act[nn * 37 + (pz * 2 + ohl) * 6 + ow] = mx;
        }
      }
    }
    __syncthreads();
    // q = act . Wet (wave-split over channels) + be
    {
      float qpv = 0.f;
      const int n = ln;
#pragma unroll 2
      for (int c2 = wv * 16; c2 < wv * 16 + 16; c2++)
        for (int hw = 0; hw < 36; hw++)
          qpv = fmaf(act[c2 * 37 + hw], Wet[(c2 * 36 + hw) * 64 + n], qpv);
      qp[wv * 64 + n] = qpv;
    }
    __syncthreads();
    if (tid < 64)
      ql[tid] =
          be[tid] + qp[tid] + qp[64 + tid] + qp[128 + tid] + qp[192 + tid];
    __syncthreads();
    if (wv == 0) {
      float s = -INFINITY;
      if (ln < 36) {
        float a = 0.f;
        for (int c = 0; c < 64; c++) a = fmaf(act[c * 37 + ln], ql[c], a);
        s = a;
      }
      float mx = s;
      for (int off = 32; off >= 1; off >>= 1)
        mx = fmaxf(mx, __shfl_xor(mx, off));
      float e = (ln < 36) ? expf(s - mx) : 0.f;
      float sum = e;
      for (int off = 32; off >= 1; off >>= 1) sum += __shfl_xor(sum, off);
      if (ln < 36) sc[ln] = e / sum;
    }
    __syncthreads();
    if (wv == 0) {
      float gv = 0.f;
      for (int hw = 0; hw < 36; hw++) gv = fmaf(act[ln * 37 + hw], sc[hw], gv);
      gm[ln] = gv;
    }
    __syncthreads();
    if (tid < 7) {
      float a = fc3b[tid];
      for (int c = 0; c < 64; c++) a = fmaf(fc3w[tid * 64 + c], gm[c], a);
      out[(size_t)(b0 + blk) * 7 + tid] = a;
    }
  }
}

// ============================================================================
extern "C" void kernel_launch(void* const* d_in, const int* in_sizes, int n_in,
                              void* d_out, int out_size, void* d_ws,
                              size_t ws_size, hipStream_t stream) {
  const float* x    = (const float*)d_in[0];
  const float* c1w  = (const float*)d_in[1];
  const float* c1b  = (const float*)d_in[2];
  const float* g1   = (const float*)d_in[3];
  const float* bb1  = (const float*)d_in[4];
  const float* m1   = (const float*)d_in[5];
  const float* v1   = (const float*)d_in[6];
  const float* c2w  = (const float*)d_in[7];
  const float* c2b  = (const float*)d_in[8];
  const float* g2   = (const float*)d_in[9];
  const float* bb2  = (const float*)d_in[10];
  const float* m2   = (const float*)d_in[11];
  const float* v2   = (const float*)d_in[12];
  const float* c3w  = (const float*)d_in[13];
  const float* c3b  = (const float*)d_in[14];
  const float* g3   = (const float*)d_in[15];
  const float* bb3  = (const float*)d_in[16];
  const float* m3   = (const float*)d_in[17];
  const float* v3   = (const float*)d_in[18];
  const float* fc1w = (const float*)d_in[19];
  const float* fc1b = (const float*)d_in[20];
  const float* fc2w = (const float*)d_in[21];
  const float* fc2b = (const float*)d_in[22];
  const float* attw = (const float*)d_in[23];
  const float* attb = (const float*)d_in[24];
  const float* fc3w = (const float*)d_in[25];
  const float* fc3b = (const float*)d_in[26];

  const size_t PER_CHUNK = (173056ULL + 25088ULL) * 2;  // bytes per image
  const size_t PERSIST = 589824 + 147456 + 131072 + 589824 + 256 + 8192;
  int CH = 512;
  while (CH > 8 && (size_t)CH * PER_CHUNK + PERSIST > ws_size) CH >>= 1;
  const int NCHK = 512 / CH;

  char* base = (char*)d_ws;
  size_t off = 0;
  auto alloc = [&](size_t nbytes) -> void* {
    void* p = base + off;
    off = (off + nbytes + 255) & ~(size_t)255;
    return p;
  };
  __hip_bfloat16* out1p = (__hip_bfloat16*)alloc((size_t)CH * 173056 * 2);
  __hip_bfloat16* out2p = (__hip_bfloat16*)alloc((size_t)CH * 25088 * 2);
  __hip_bfloat16* wt2  = (__hip_bfloat16*)alloc(589824);
  __hip_bfloat16* wt3  = (__hip_bfloat16*)alloc(147456);
  float* W32           = (float*)alloc(131072);
  float* Wet           = (float*)alloc(589824);
  float* be            = (float*)alloc(256);

  k_prep<<<1569, 256, 0, stream>>>(c2w, wt2, c3w, wt3, attw, fc2w, W32, fc1b,
                                   fc2b, attb, be);
  k_weff<<<576, 256, 0, stream>>>(W32, fc1w, Wet);

  for (int c = 0; c < NCHK; c++) {
    const float* xc = x + (size_t)c * CH * 2304;
    k_pipe<<<CH, 256, 0, stream>>>(xc, c1w, c1b, g1, bb1, m1, v1, out1p, out2p,
                                   wt2, c2b, g2, bb2, m2, v2, wt3, c3b, g3,
                                   bb3, m3, v3, Wet, be, fc3w, fc3b,
                                   (float*)d_out, c * CH);
  }
}

// Round 15
// 438.764 us; speedup vs baseline: 2.8808x; 2.8808x over previous
//
#include <hip/hip_runtime.h>
#include <hip/hip_bf16.h>
#include <math.h>

#define EPS_BN 1e-5f

typedef __bf16 bf16x8 __attribute__((ext_vector_type(8)));
typedef float f32x4 __attribute__((ext_vector_type(4)));
typedef float f32x16 __attribute__((ext_vector_type(16)));
typedef float f32x2 __attribute__((ext_vector_type(2)));

// async global->LDS, 16B per lane. LDS dest must be wave-uniform base + lane*16
__device__ __forceinline__ void gl2lds16(const void* g, void* l) {
  __builtin_amdgcn_global_load_lds(
      (const __attribute__((address_space(1))) unsigned int*)g,
      (__attribute__((address_space(3))) unsigned int*)l, 16, 0, 0);
}

// ============================================================================
// conv1 + bias + BN + ReLU + maxpool2 (+ fused out2p halo zero + fused W_eff).
// blocks [0, n1):      conv1 band path -> out1p padded bf16 NHWC [26][26][256]
// blocks [n1, n1+576): W_eff = W32 @ fc1_w stored transposed [2304][64]
// ============================================================================
__global__ __launch_bounds__(256) void k_conv1(
    const float* __restrict__ x, const float* __restrict__ w,
    const float* __restrict__ cb, const float* __restrict__ g,
    const float* __restrict__ bb, const float* __restrict__ m,
    const float* __restrict__ v, __hip_bfloat16* __restrict__ out1p,
    __hip_bfloat16* __restrict__ out2p, const float* __restrict__ W32,
    const float* __restrict__ fc1w, float* __restrict__ Wet, int n1) {
  __shared__ float xp[14 * 50];
  const int bq = blockIdx.x;
  const int t = threadIdx.x;
  if (bq >= n1) {  // ---- fused W_eff path ----
    int idx = (bq - n1) * 256 + t;  // 64*2304
    int r = idx / 2304, c = idx - r * 2304;
    float s = 0.f;
    for (int k = 0; k < 512; k++)
      s = fmaf(W32[r * 512 + k], fc1w[k * 2304 + c], s);
    Wet[c * 64 + r] = s;  // transposed store
    return;
  }
  const int b = bq >> 2, q = bq & 3;  // band q: output rows 6q..6q+5
  __hip_bfloat16* ob = out1p + (size_t)b * (26 * 26 * 256);
  const __hip_bfloat16 z = __float2bfloat16(0.f);
  if (q == 0)
    for (int i = t; i < 26 * 256; i += 256) ob[i] = z;
  if (q == 3)
    for (int i = t; i < 26 * 256; i += 256) ob[25 * 26 * 256 + i] = z;
  for (int i = t; i < 6 * 2 * 256; i += 256) {
    int r = 1 + 6 * q + (i >> 9), side = (i >> 8) & 1, c = i & 255;
    ob[(r * 26 + side * 25) * 256 + c] = z;
  }
  {
    __hip_bfloat16* o2 = out2p + (size_t)b * (14 * 14 * 128);
    if (q == 0)
      for (int i = t; i < 14 * 128; i += 256) o2[i] = z;
    if (q == 1)
      for (int i = t; i < 14 * 128; i += 256) o2[13 * 14 * 128 + i] = z;
    if (q == 2)
      for (int i = t; i < 6 * 2 * 128; i += 256) {
        int r = 1 + (i >> 8), side = (i >> 7) & 1, c = i & 127;
        o2[(r * 14 + side * 13) * 128 + c] = z;
      }
    if (q == 3)
      for (int i = t; i < 6 * 2 * 128; i += 256) {
        int r = 7 + (i >> 8), side = (i >> 7) & 1, c = i & 127;
        o2[(r * 14 + side * 13) * 128 + c] = z;
      }
  }
  for (int i = t; i < 14 * 50; i += 256) xp[i] = 0.f;
  __syncthreads();
  const float* xb = x + (size_t)b * 2304;
  for (int i = t; i < 14 * 48; i += 256) {
    int rr = i / 48, c = i - rr * 48;
    int gr = 12 * q - 1 + rr;
    if (gr >= 0 && gr < 48) xp[rr * 50 + c + 1] = xb[gr * 48 + c];
  }
  __syncthreads();
  float wr[9];
#pragma unroll
  for (int i = 0; i < 9; i++) wr[i] = w[t * 9 + i];
  const float scale = g[t] * rsqrtf(v[t] + EPS_BN);
  const float bias = (cb[t] - m[t]) * scale + bb[t];
#pragma unroll
  for (int ohl = 0; ohl < 6; ohl++) {
    const int r0 = 2 * ohl;
    f32x2 c01[4];
#pragma unroll
    for (int r = 0; r < 4; r++) c01[r] = *(const f32x2*)&xp[(r0 + r) * 50];
#pragma unroll 4
    for (int ow = 0; ow < 24; ow++) {
      f32x2 c23[4];
#pragma unroll
      for (int r = 0; r < 4; r++)
        c23[r] = *(const f32x2*)&xp[(r0 + r) * 50 + 2 * ow + 2];
      f32x2 s2a = 0.f, s2b = 0.f;  // dh = 0, 1 (packed over dw)
#pragma unroll
      for (int r = 0; r < 4; r++) {
        f32x2 p0 = c01[r], p2 = c23[r];
        f32x2 p1 = {p0.y, p2.x};
        if (r <= 2) {
          s2a += p0 * wr[r * 3 + 0];
          s2a += p1 * wr[r * 3 + 1];
          s2a += p2 * wr[r * 3 + 2];
        }
        if (r >= 1) {
          s2b += p0 * wr[(r - 1) * 3 + 0];
          s2b += p1 * wr[(r - 1) * 3 + 1];
          s2b += p2 * wr[(r - 1) * 3 + 2];
        }
      }
      f32x2 e0 = s2a * scale + bias;  // BN before pool
      f32x2 e1 = s2b * scale + bias;
      float mx = fmaxf(fmaxf(e0.x, e0.y), fmaxf(e1.x, e1.y));
      ob[((6 * q + ohl + 1) * 26 + (ow + 1)) * 256 + t] =
          __float2bfloat16(fmaxf(mx, 0.f));
#pragma unroll
      for (int r = 0; r < 4; r++) c01[r] = c23[r];
    }
  }
}

// ============================================================================
// Fused weight prep (one launch):
//   blocks [0,1152):    conv2 w -> bf16 [9][16][2][128][8] (32x32x16 B-frag:
//                       n=lane&31, k=(lane>>5)*8+j -> khalf-major segments)
//   blocks [1152,1440): conv3 w -> bf16 [9][16][64][8] (16x16x32 layout)
//   blocks [1440,1568): W32 = att_w[64,256] @ fc2_w[256,512]
//   block  1568:        b_eff = att_w@(fc2_w@fc1_b + fc2_b) + att_b
// ============================================================================
__global__ void k_prep(const float* __restrict__ c2w,
                       __hip_bfloat16* __restrict__ wt2,
                       const float* __restrict__ c3w,
                       __hip_bfloat16* __restrict__ wt3,
                       const float* __restrict__ attw,
                       const float* __restrict__ fc2w, float* __restrict__ W32,
                       const float* __restrict__ fc1b,
                       const float* __restrict__ fc2b,
                       const float* __restrict__ attb, float* __restrict__ be) {
  const int blk = blockIdx.x, tid = threadIdx.x;
  if (blk < 1152) {  // conv2 wt: [9][16][2][128][8]
    int idx = blk * 256 + tid;
    int icr = idx & 7;
    int oc = (idx >> 3) & 127;
    int kh = (idx >> 10) & 1;
    int kbg = (idx >> 11) & 15;
    int p = idx >> 15;
    int ic = kbg * 16 + kh * 8 + icr;
    wt2[idx] = __float2bfloat16(c2w[(oc * 256 + ic) * 9 + p]);
  } else if (blk < 1440) {  // conv3 wt: [9][16][64][8]
    int idx = (blk - 1152) * 256 + tid;
    int icr = idx & 7;
    int oc = (idx >> 3) & 63;
    int rest = idx >> 9;
    int icg = rest & 15;
    int p = rest >> 4;
    wt3[idx] = __float2bfloat16(c3w[(oc * 128 + icg * 8 + icr) * 9 + p]);
  } else if (blk < 1568) {
    int idx = (blk - 1440) * 256 + tid;
    int r = idx >> 9, c = idx & 511;
    float s = 0.f;
    for (int k = 0; k < 256; k++)
      s = fmaf(attw[r * 256 + k], fc2w[k * 512 + c], s);
    W32[idx] = s;
  } else {
    __shared__ float t1[256];
    float s = fc2b[tid];
    for (int k = 0; k < 512; k++) s = fmaf(fc2w[tid * 512 + k], fc1b[k], s);
    t1[tid] = s;
    __syncthreads();
    if (tid < 64) {
      float r = attb[tid];
      for (int k = 0; k < 256; k++) r = fmaf(attw[tid * 256 + k], t1[k], r);
      be[tid] = r;
    }
  }
}

// ============================================================================
// conv2 via mfma_f32_32x32x16_bf16: 4 waves SHARE M=96 (3 m-frags of 32 rows),
// each wave owns 32 oc (NF=1). Per 16-k step: 1 B-load feeds 3 MFMA (~24 cyc
// of issue vs 14.5 in the 16x16 config) and total B-loads/wave halve (144 vs
// 288) — attacks the measured per-step B-load-latency plateau. acc = 48 AGPR
// (3 x f32x16), no ring (R9/R10/R13 all showed rings push regs past 170).
// A window/LDS/swizzle/DMA identical to R12 (best measured). XCD swizzle kept.
// C/D map (verified m74/m101): col=lane&31, row=(reg&3)+8*(reg>>2)+4*(lane>>5).
// ============================================================================
__global__ __launch_bounds__(256) void k_mconv2(
    const __hip_bfloat16* __restrict__ in, const __hip_bfloat16* __restrict__ wt,
    const float* __restrict__ cb, const float* __restrict__ gg,
    const float* __restrict__ bbv, const float* __restrict__ bm,
    const float* __restrict__ bv, __hip_bfloat16* __restrict__ outp) {
  constexpr int HW = 24, IC = 256, OC = 128, HP = 26, CP = 26;
  constexpr int NCH = 6 * CP * 8;           // 1248 16B slots per window
  constexpr int NCHP = (NCH + 255) & ~255;  // 1280
  constexpr int NLD = NCHP / 256;           // 5
  constexpr int NSTG = 4;
  constexpr int ABUF = NCHP * 16;  // 20480 B per window
  constexpr int EPITCH = OC + 1;   // 129
  constexpr int SMB = 2 * ABUF;    // 40960 (se 48*129*4=24768 fits inside)

  __shared__ __align__(16) char smraw[SMB];
  float* se = (float*)smraw;

  const int tid = threadIdx.x;
  const int wn = tid >> 6, ln = tid & 63;
  const int l31 = ln & 31, khalf = ln >> 5;

  // XCD-aware remap: all 6 tiles of an image on one XCD's L2.
  const int per = gridDim.x >> 3;
  const int xcd = blockIdx.x & 7, sl = blockIdx.x >> 3;
  const int b = xcd * (per / 6) + sl / 6;
  const int T = sl % 6;
  const int h0 = T * 4;

  const __hip_bfloat16* inb = in + (size_t)b * HP * HP * IC;

  // staging source map (identical to R12)
  int srcoff[NLD];
#pragma unroll
  for (int i = 0; i < NLD; i++) {
    int ci = tid + i * 256;
    if (ci >= NCH) ci = NCH - 1;
    int kgslot = ci & 7;
    int rest = ci >> 3;
    int c = rest % CP;
    int r = rest / CP;
    int kg = kgslot ^ (c & 7);
    srcoff[i] = ((h0 + r) * HP + c) * IC + kg * 8;
  }
  // A-frag spatial bases: m = mt*32 + l31
  int spb[3], wlv[3];
#pragma unroll
  for (int mt = 0; mt < 3; mt++) {
    int m = mt * 32 + l31;
    int hl = m / HW, wl = m % HW;
    spb[mt] = (hl * CP + wl) * 8;
    wlv[mt] = wl;
  }
  // B lane base: oc = wn*32 + l31, khalf segment
  const __hip_bfloat16* wtb = wt + (size_t)(khalf * OC + wn * 32 + l31) * 8;

  f32x16 acc[3];
#pragma unroll
  for (int i = 0; i < 3; i++)
#pragma unroll
    for (int r = 0; r < 16; r++) acc[i][r] = 0.f;

  // prologue: DMA stage 0 into window 0
#pragma unroll
  for (int i = 0; i < NLD; i++)
    gl2lds16(inb + srcoff[i], smraw + (tid + i * 256) * 16);
  __syncthreads();

#pragma unroll
  for (int s = 0; s < NSTG; s++) {
    if (s + 1 < NSTG) {  // prefetch next stage into other window
      char* nb = smraw + ((s + 1) & 1) * ABUF;
#pragma unroll
      for (int i = 0; i < NLD; i++)
        gl2lds16(inb + srcoff[i] + (s + 1) * 64, nb + (tid + i * 256) * 16);
    }
    const char* cw = smraw + (s & 1) * ABUF;
#pragma unroll
    for (int p = 0; p < 9; p++) {
      const int ph = p / 3, pw = p % 3;
#pragma unroll
      for (int kb = 0; kb < 4; kb++) {  // 16-ic steps within the 64-ic window
        const int kg = kb * 2 + khalf;
        bf16x8 bf =
            *(const bf16x8*)(wtb + (size_t)(p * 16 + s * 4 + kb) * 2048);
#pragma unroll
        for (int mt = 0; mt < 3; mt++) {
          int slot = spb[mt] + (ph * CP + pw) * 8 + (kg ^ ((wlv[mt] + pw) & 7));
          bf16x8 af = *(const bf16x8*)(cw + slot * 16);
          acc[mt] = __builtin_amdgcn_mfma_f32_32x32x16_bf16(af, bf, acc[mt], 0,
                                                            0, 0);
        }
      }
    }
    __syncthreads();  // window s reads done; DMA for s+1 drained
  }

  // ---- epilogue: 2 passes of 48 m-rows (2 h-rows): BN+ReLU -> se, pool, store
  const int n = wn * 32 + l31;
  const float scale = gg[n] * rsqrtf(bv[n] + EPS_BN);
  const float bias = (cb[n] - bm[n]) * scale + bbv[n];
  constexpr int OHW = 12;
#pragma unroll
  for (int pz = 0; pz < 2; pz++) {
    if (pz) __syncthreads();
#pragma unroll
    for (int mt = 0; mt < 3; mt++)
#pragma unroll
      for (int r = 0; r < 16; r++) {
        const int rl0 = (r & 3) + 8 * (r >> 2);  // compile-time
        const int m0 = mt * 32 + rl0;            // m = m0 + 4*khalf
        if ((pz == 0 && m0 < 48) || (pz == 1 && m0 >= 48)) {
          int mrow = m0 + 4 * khalf - pz * 48;
          se[mrow * EPITCH + n] = fmaxf(acc[mt][r] * scale + bias, 0.f);
        }
      }
    __syncthreads();
    for (int sI = tid; sI < OHW * OC; sI += 256) {
      int n2 = sI % OC;
      int ow = sI / OC;
      int mloc = 2 * ow;
      float x0 = se[mloc * EPITCH + n2];
      float x1 = se[(mloc + 1) * EPITCH + n2];
      float x2 = se[(mloc + HW) * EPITCH + n2];
      float x3 = se[(mloc + HW + 1) * EPITCH + n2];
      float mx = fmaxf(fmaxf(x0, x1), fmaxf(x2, x3));
      int oh = T * 2 + pz;
      // padded bf16 NHWC [14][14][128], interior at +1
      outp[(((size_t)b * 14 + oh + 1) * 14 + ow + 1) * OC + n2] =
          __float2bfloat16(mx);
    }
  }
}

// ============================================================================
// FUSED conv3 + BN + ReLU + pool + spatial attention + fc3. One block/image.
// (R12-exact — measured good)
// ============================================================================
__global__ __launch_bounds__(256) void k_c3attn(
    const __hip_bfloat16* __restrict__ in, const __hip_bfloat16* __restrict__ wt,
    const float* __restrict__ cb, const float* __restrict__ gg,
    const float* __restrict__ bbv, const float* __restrict__ bm,
    const float* __restrict__ bv, const float* __restrict__ Wet,
    const float* __restrict__ be, const float* __restrict__ w3,
    const float* __restrict__ b3, float* __restrict__ out, int b0) {
  constexpr int HW = 12, IC = 128, OC = 64, HP = 14, CP = 14;
  constexpr int NCH = 14 * CP * 8;
  constexpr int NCHP = (NCH + 255) & ~255;
  constexpr int NLD = NCHP / 256;
  constexpr int NSTG = 2;
  constexpr int ABUF = NCHP * 16;
  constexpr int ICG = 16;
  constexpr int EPITCH = OC + 1;

  __shared__ __align__(16) char smraw[2 * ABUF];
  __shared__ float act[64 * 37];
  __shared__ float qp[4][64];
  __shared__ float ql[64], gm[64], sc[36];
  float* se = (float*)smraw;

  const int tid = threadIdx.x;
  const int wv = tid >> 6, ln = tid & 63;
  const int lhi = ln >> 4, llo = ln & 15;
  const int b = blockIdx.x;

  const __hip_bfloat16* inb = in + (size_t)b * HP * HP * IC;

  int srcoff[NLD];
#pragma unroll
  for (int i = 0; i < NLD; i++) {
    int ci = tid + i * 256;
    if (ci >= NCH) ci = NCH - 1;
    int kgslot = ci & 7;
    int rest = ci >> 3;
    int c = rest % CP;
    int r = rest / CP;
    int kg = kgslot ^ (c & 7);
    srcoff[i] = (r * HP + c) * IC + kg * 8;
  }
  int spb[9], wlv[9];
#pragma unroll
  for (int mt = 0; mt < 9; mt++) {
    int m = mt * 16 + llo;
    int hl = m / HW, wl = m % HW;
    spb[mt] = (hl * CP + wl) * 8;
    wlv[mt] = wl;
  }
  const __hip_bfloat16* wtb = wt + (size_t)(lhi * OC + wv * 16 + llo) * 8;

  f32x4 acc[9];
  const f32x4 fz = {0.f, 0.f, 0.f, 0.f};
#pragma unroll
  for (int i = 0; i < 9; i++) acc[i] = fz;

#pragma unroll
  for (int i = 0; i < NLD; i++)
    gl2lds16(inb + srcoff[i], smraw + (tid + i * 256) * 16);
  __syncthreads();

#pragma unroll
  for (int s = 0; s < NSTG; s++) {
    if (s + 1 < NSTG) {
      char* nb = smraw + ((s + 1) & 1) * ABUF;
#pragma unroll
      for (int i = 0; i < NLD; i++)
        gl2lds16(inb + srcoff[i] + (s + 1) * 64, nb + (tid + i * 256) * 16);
    }
    const char* cw = smraw + (s & 1) * ABUF;
#pragma unroll
    for (int tt = 0; tt < 18; tt++) {
      const int p = tt >> 1, ks = tt & 1;
      const int ph = p / 3, pw = p % 3;
      const int kg = ks * 4 + lhi;
      bf16x8 bf =
          *(const bf16x8*)(wtb + ((size_t)(p * ICG + s * 8 + ks * 4) * OC) * 8);
#pragma unroll
      for (int mt = 0; mt < 9; mt++) {
        int slot = spb[mt] + (ph * CP + pw) * 8 + (kg ^ ((wlv[mt] + pw) & 7));
        bf16x8 af = *(const bf16x8*)(cw + slot * 16);
        acc[mt] = __builtin_amdgcn_mfma_f32_16x16x32_bf16(af, bf, acc[mt], 0,
                                                          0, 0);
      }
    }
    __syncthreads();
  }

  {
    const int n = wv * 16 + llo;
    const float scale = gg[n] * rsqrtf(bv[n] + EPS_BN);
    const float bias = (cb[n] - bm[n]) * scale + bbv[n];
#pragma unroll
    for (int pz = 0; pz < 3; pz++) {
      if (pz) __syncthreads();
#pragma unroll
      for (int mtl = 0; mtl < 3; mtl++)
#pragma unroll
        for (int r = 0; r < 4; r++) {
          int mrow = mtl * 16 + lhi * 4 + r;
          se[mrow * EPITCH + n] =
              fmaxf(acc[pz * 3 + mtl][r] * scale + bias, 0.f);
        }
      __syncthreads();
      for (int sI = tid; sI < 2 * 6 * 64; sI += 256) {
        int nn = sI % 64;
        int ow = (sI / 64) % 6;
        int ohl = sI / (64 * 6);
        int mloc = (2 * ohl) * HW + 2 * ow;
        float x0 = se[mloc * EPITCH + nn];
        float x1 = se[(mloc + 1) * EPITCH + nn];
        float x2 = se[(mloc + HW) * EPITCH + nn];
        float x3 = se[(mloc + HW + 1) * EPITCH + nn];
        float mx = fmaxf(fmaxf(x0, x1), fmaxf(x2, x3));
        act[nn * 37 + (pz * 2 + ohl) * 6 + ow] = mx;
      }
    }
  }
  __syncthreads();

  {
    float qpv = 0.f;
    const int n = ln;
#pragma unroll 2
    for (int c2 = wv * 16; c2 < wv * 16 + 16; c2++)
      for (int hw = 0; hw < 36; hw++)
        qpv = fmaf(act[c2 * 37 + hw], Wet[(c2 * 36 + hw) * 64 + n], qpv);
    qp[wv][n] = qpv;
  }
  __syncthreads();
  if (tid < 64)
    ql[tid] = be[tid] + qp[0][tid] + qp[1][tid] + qp[2][tid] + qp[3][tid];
  __syncthreads();
  if (wv == 0) {
    float s = -INFINITY;
    if (ln < 36) {
      float a = 0.f;
      for (int c = 0; c < 64; c++) a = fmaf(act[c * 37 + ln], ql[c], a);
      s = a;
    }
    float mx = s;
    for (int off = 32; off >= 1; off >>= 1)
      mx = fmaxf(mx, __shfl_xor(mx, off));
    float e = (ln < 36) ? expf(s - mx) : 0.f;
    float sum = e;
    for (int off = 32; off >= 1; off >>= 1) sum += __shfl_xor(sum, off);
    if (ln < 36) sc[ln] = e / sum;
  }
  __syncthreads();
  if (wv == 0) {
    float gv = 0.f;
    for (int hw = 0; hw < 36; hw++) gv = fmaf(act[ln * 37 + hw], sc[hw], gv);
    gm[ln] = gv;
  }
  __syncthreads();
  if (tid < 7) {
    float a = b3[tid];
    for (int c = 0; c < 64; c++) a = fmaf(w3[tid * 64 + c], gm[c], a);
    out[(size_t)(b0 + b) * 7 + tid] = a;
  }
}

// ============================================================================
extern "C" void kernel_launch(void* const* d_in, const int* in_sizes, int n_in,
                              void* d_out, int out_size, void* d_ws,
                              size_t ws_size, hipStream_t stream) {
  const float* x    = (const float*)d_in[0];
  const float* c1w  = (const float*)d_in[1];
  const float* c1b  = (const float*)d_in[2];
  const float* g1   = (const float*)d_in[3];
  const float* bb1  = (const float*)d_in[4];
  const float* m1   = (const float*)d_in[5];
  const float* v1   = (const float*)d_in[6];
  const float* c2w  = (const float*)d_in[7];
  const float* c2b  = (const float*)d_in[8];
  const float* g2   = (const float*)d_in[9];
  const float* bb2  = (const float*)d_in[10];
  const float* m2   = (const float*)d_in[11];
  const float* v2   = (const float*)d_in[12];
  const float* c3w  = (const float*)d_in[13];
  const float* c3b  = (const float*)d_in[14];
  const float* g3   = (const float*)d_in[15];
  const float* bb3  = (const float*)d_in[16];
  const float* m3   = (const float*)d_in[17];
  const float* v3   = (const float*)d_in[18];
  const float* fc1w = (const float*)d_in[19];
  const float* fc1b = (const float*)d_in[20];
  const float* fc2w = (const float*)d_in[21];
  const float* fc2b = (const float*)d_in[22];
  const float* attw = (const float*)d_in[23];
  const float* attb = (const float*)d_in[24];
  const float* fc3w = (const float*)d_in[25];
  const float* fc3b = (const float*)d_in[26];

  const size_t PER_CHUNK = (173056ULL + 25088ULL) * 2;  // bytes per image
  const size_t PERSIST = 589824 + 147456 + 131072 + 589824 + 256 + 8192;
  int CH = 512;
  while (CH > 8 && (size_t)CH * PER_CHUNK + PERSIST > ws_size) CH >>= 1;
  const int NCHK = 512 / CH;

  char* base = (char*)d_ws;
  size_t off = 0;
  auto alloc = [&](size_t nbytes) -> void* {
    void* p = base + off;
    off = (off + nbytes + 255) & ~(size_t)255;
    return p;
  };
  __hip_bfloat16* out1p = (__hip_bfloat16*)alloc((size_t)CH * 173056 * 2);
  __hip_bfloat16* out2p = (__hip_bfloat16*)alloc((size_t)CH * 25088 * 2);
  __hip_bfloat16* wt2  = (__hip_bfloat16*)alloc(589824);
  __hip_bfloat16* wt3  = (__hip_bfloat16*)alloc(147456);
  float* W32           = (float*)alloc(131072);
  float* Wet           = (float*)alloc(589824);
  float* be            = (float*)alloc(256);

  k_prep<<<1569, 256, 0, stream>>>(c2w, wt2, c3w, wt3, attw, fc2w, W32, fc1b,
                                   fc2b, attb, be);

  for (int c = 0; c < NCHK; c++) {
    const float* xc = x + (size_t)c * CH * 2304;
    const int n1 = CH * 4;
    const int grid1 = n1 + (c == 0 ? 576 : 0);  // W_eff fused in chunk 0
    k_conv1<<<grid1, 256, 0, stream>>>(xc, c1w, c1b, g1, bb1, m1, v1, out1p,
                                       out2p, W32, fc1w, Wet, n1);
    k_mconv2<<<CH * 6, 256, 0, stream>>>(out1p, wt2, c2b, g2, bb2, m2, v2,
                                         out2p);
    k_c3attn<<<CH, 256, 0, stream>>>(out2p, wt3, c3b, g3, bb3, m3, v3, Wet, be,
                                     fc3w, fc3b, (float*)d_out, c * CH);
  }
}